// Round 4
// baseline (220.233 us; speedup 1.0000x reference)
//
#include <hip/hip_runtime.h>
#include <hip/hip_bf16.h>
#include <math.h>

#define N_NODES 40000
#define N_EDGES 640000
#define D 128
#define LN_EPS 1e-5f
#define SCAN_B 512
#define SCAN_NB ((N_NODES + SCAN_B - 1) / SCAN_B)   // 79

__device__ __forceinline__ float f4get(const float4& v, int j) {
    return j == 0 ? v.x : j == 1 ? v.y : j == 2 ? v.z : v.w;
}

// ---------------------------------------------------------------------------
// GEMM: hpack[node][feat] = float2( x@Wm+bm , exp(x@Wv+bv) )
// ---------------------------------------------------------------------------
__global__ __launch_bounds__(256) void gemm_kernel(
    const float* __restrict__ x, const float* __restrict__ Wm,
    const float* __restrict__ bm, const float* __restrict__ Wv,
    const float* __restrict__ bv, float2* __restrict__ hpack)
{
    __shared__ float xs[64][24];
    __shared__ float wms[16][128];
    __shared__ float wvs[16][128];

    const int t = threadIdx.x;
    const int nbase = blockIdx.x * 64;
    const int tx = t & 31;
    const int ty = t >> 5;

    float accm[8][4] = {};
    float accv[8][4] = {};

    for (int k0 = 0; k0 < D; k0 += 16) {
        if (k0) __syncthreads();
        {
            int row = t >> 2, c4 = (t & 3) << 2;
            float4 v = *(const float4*)&x[(size_t)(nbase + row) * D + k0 + c4];
            xs[row][c4 + 0] = v.x; xs[row][c4 + 1] = v.y;
            xs[row][c4 + 2] = v.z; xs[row][c4 + 3] = v.w;
        }
        #pragma unroll
        for (int j = 0; j < 2; ++j) {
            int f4 = t + 256 * j;
            int row = f4 >> 5, c4 = (f4 & 31) << 2;
            *(float4*)&wms[row][c4] = *(const float4*)&Wm[(size_t)(k0 + row) * D + c4];
            *(float4*)&wvs[row][c4] = *(const float4*)&Wv[(size_t)(k0 + row) * D + c4];
        }
        __syncthreads();

        #pragma unroll
        for (int kk4 = 0; kk4 < 4; ++kk4) {
            float4 xr[8];
            #pragma unroll
            for (int r = 0; r < 8; ++r)
                xr[r] = *(float4*)&xs[ty * 8 + r][kk4 * 4];
            #pragma unroll
            for (int j = 0; j < 4; ++j) {
                float4 wm4 = *(float4*)&wms[kk4 * 4 + j][tx * 4];
                float4 wv4 = *(float4*)&wvs[kk4 * 4 + j][tx * 4];
                #pragma unroll
                for (int r = 0; r < 8; ++r) {
                    float xv = f4get(xr[r], j);
                    accm[r][0] = fmaf(xv, wm4.x, accm[r][0]);
                    accm[r][1] = fmaf(xv, wm4.y, accm[r][1]);
                    accm[r][2] = fmaf(xv, wm4.z, accm[r][2]);
                    accm[r][3] = fmaf(xv, wm4.w, accm[r][3]);
                    accv[r][0] = fmaf(xv, wv4.x, accv[r][0]);
                    accv[r][1] = fmaf(xv, wv4.y, accv[r][1]);
                    accv[r][2] = fmaf(xv, wv4.z, accv[r][2]);
                    accv[r][3] = fmaf(xv, wv4.w, accv[r][3]);
                }
            }
        }
    }

    float4 bm4 = *(const float4*)&bm[tx * 4];
    float4 bv4 = *(const float4*)&bv[tx * 4];
    #pragma unroll
    for (int r = 0; r < 8; ++r) {
        size_t node = nbase + ty * 8 + r;
        float m0 = accm[r][0] + bm4.x, m1 = accm[r][1] + bm4.y;
        float m2 = accm[r][2] + bm4.z, m3 = accm[r][3] + bm4.w;
        float v0 = expf(accv[r][0] + bv4.x), v1 = expf(accv[r][1] + bv4.y);
        float v2 = expf(accv[r][2] + bv4.z), v3 = expf(accv[r][3] + bv4.w);
        float4* dst = (float4*)&hpack[node * D + tx * 4];
        dst[0] = make_float4(m0, v0, m1, v1);
        dst[1] = make_float4(m2, v2, m3, v3);
    }
}

// ---------------------------------------------------------------------------
__global__ void hist_kernel(const int* __restrict__ row, int* __restrict__ counts)
{
    int e = blockIdx.x * blockDim.x + threadIdx.x;
    if (e < N_EDGES) atomicAdd(&counts[row[e]], 1);
}

// ---------------------------------------------------------------------------
__global__ __launch_bounds__(SCAN_B) void scan_partial_kernel(
    const int* __restrict__ counts, int* __restrict__ partials)
{
    int idx = blockIdx.x * SCAN_B + threadIdx.x;
    int c = (idx < N_NODES) ? counts[idx] : 0;
    int lane = threadIdx.x & 63, wid = threadIdx.x >> 6;
    #pragma unroll
    for (int off = 32; off >= 1; off >>= 1) c += __shfl_xor(c, off);
    __shared__ int ws[SCAN_B / 64];
    if (lane == 0) ws[wid] = c;
    __syncthreads();
    if (threadIdx.x == 0) {
        int s = 0;
        #pragma unroll
        for (int i = 0; i < SCAN_B / 64; ++i) s += ws[i];
        partials[blockIdx.x] = s;
    }
}

// ---------------------------------------------------------------------------
__global__ __launch_bounds__(128) void scan_top_kernel(
    const int* __restrict__ partials, int* __restrict__ blockoff)
{
    __shared__ int tmp[128];
    int t = threadIdx.x;
    tmp[t] = (t < SCAN_NB) ? partials[t] : 0;
    __syncthreads();
    for (int off = 1; off < 128; off <<= 1) {
        int v = tmp[t];
        int a = (t >= off) ? tmp[t - off] : 0;
        __syncthreads();
        tmp[t] = v + a;
        __syncthreads();
    }
    if (t < SCAN_NB) blockoff[t] = (t > 0) ? tmp[t - 1] : 0;
}

// ---------------------------------------------------------------------------
__global__ __launch_bounds__(SCAN_B) void scan_write_kernel(
    const int* __restrict__ counts, const int* __restrict__ blockoff,
    int* __restrict__ rowstart, int* __restrict__ cursor)
{
    int idx = blockIdx.x * SCAN_B + threadIdx.x;
    int c = (idx < N_NODES) ? counts[idx] : 0;
    int lane = threadIdx.x & 63, wid = threadIdx.x >> 6;

    int inc = c;
    #pragma unroll
    for (int off = 1; off < 64; off <<= 1) {
        int u = __shfl_up(inc, off);
        if (lane >= off) inc += u;
    }
    __shared__ int ws[SCAN_B / 64];
    if (lane == 63) ws[wid] = inc;
    __syncthreads();
    if (threadIdx.x == 0) {
        int run = 0;
        #pragma unroll
        for (int i = 0; i < SCAN_B / 64; ++i) { int v = ws[i]; ws[i] = run; run += v; }
    }
    __syncthreads();
    int excl = inc - c + ws[wid] + blockoff[blockIdx.x];
    if (idx < N_NODES) {
        rowstart[idx] = excl;
        cursor[idx]   = excl;
        if (idx == N_NODES - 1) rowstart[N_NODES] = excl + c;
    }
}

// ---------------------------------------------------------------------------
// Scatter edges into CSR order, packed: epack[pos] = {colbits, wm, wv, 0}
// ---------------------------------------------------------------------------
__global__ void scatter_kernel(
    const int* __restrict__ row, const int* __restrict__ col,
    const float* __restrict__ ewm, const float* __restrict__ ewv,
    int* __restrict__ cursor, float4* __restrict__ epack)
{
    int e = blockIdx.x * blockDim.x + threadIdx.x;
    if (e >= N_EDGES) return;
    int r = row[e];
    int pos = atomicAdd(&cursor[r], 1);
    epack[pos] = make_float4(__int_as_float(col[e]), ewm[e], ewv[e], 0.0f);
}

// ---------------------------------------------------------------------------
// Per-node aggregation + degree normalization + LayerNorm.
// ONE WAVE PER NODE: 64 lanes x float4 = whole 1KB row per gather.
// LN fully in-wave via shuffles — no LDS, no __syncthreads.
// ---------------------------------------------------------------------------
__global__ __launch_bounds__(256) void agg_kernel(
    const float4* __restrict__ hp,     // hpack viewed as float4: [node][64]
    const int* __restrict__ rowstart,
    const float4* __restrict__ epack,
    const float* __restrict__ gamma, const float* __restrict__ beta,
    float* __restrict__ out)
{
    const int wid = threadIdx.x >> 6;
    const int lane = threadIdx.x & 63;
    const int n = blockIdx.x * 4 + wid;

    const int start = __builtin_amdgcn_readfirstlane(rowstart[n]);
    const int end   = __builtin_amdgcn_readfirstlane(rowstart[n + 1]);

    // lane holds feats {2*lane, 2*lane+1}: h4 = (m0, v0, m1, v1)
    float am0 = 0.f, av0 = 0.f, am1 = 0.f, av1 = 0.f;
    int e = start;
    for (; e + 4 <= end; e += 4) {
        float4 m[4], h[4];
        #pragma unroll
        for (int i = 0; i < 4; ++i) m[i] = epack[e + i];
        #pragma unroll
        for (int i = 0; i < 4; ++i) {
            int c = __float_as_int(m[i].x);
            h[i] = hp[(size_t)c * 64 + lane];
        }
        #pragma unroll
        for (int i = 0; i < 4; ++i) {
            float wm = m[i].y, wv = m[i].z;
            am0 = fmaf(h[i].x, wm, am0);
            av0 = fmaf(wm * wm, h[i].y, fmaf(h[i].x * h[i].x, wv, av0));
            am1 = fmaf(h[i].z, wm, am1);
            av1 = fmaf(wm * wm, h[i].w, fmaf(h[i].z * h[i].z, wv, av1));
        }
    }
    for (; e < end; ++e) {
        float4 m0 = epack[e];
        int c = __float_as_int(m0.x);
        float4 h0 = hp[(size_t)c * 64 + lane];
        float wm = m0.y, wv = m0.z;
        am0 = fmaf(h0.x, wm, am0);
        av0 = fmaf(wm * wm, h0.y, fmaf(h0.x * h0.x, wv, av0));
        am1 = fmaf(h0.z, wm, am1);
        av1 = fmaf(wm * wm, h0.w, fmaf(h0.z * h0.z, wv, av1));
    }

    float degi = 1.0f / fmaxf((float)(end - start), 1.0f);
    am0 *= degi; am1 *= degi;
    float dg2 = degi * degi;
    av0 *= dg2; av1 *= dg2;

    // LayerNorm over 128 feats, in-wave
    float s = am0 + am1;
    #pragma unroll
    for (int off = 32; off >= 1; off >>= 1) s += __shfl_xor(s, off);
    float mu = s * (1.0f / 128.0f);
    float d0 = am0 - mu, d1 = am1 - mu;
    float q = d0 * d0 + d1 * d1;
    #pragma unroll
    for (int off = 32; off >= 1; off >>= 1) q += __shfl_xor(q, off);
    float var = q * (1.0f / 128.0f);
    float rs = rsqrtf(var + LN_EPS);

    float2 g = *(const float2*)&gamma[lane * 2];
    float2 b = *(const float2*)&beta[lane * 2];
    float o0 = fmaf(d0 * rs, g.x, b.x);
    float o1 = fmaf(d1 * rs, g.y, b.y);
    *(float2*)&out[(size_t)n * D + lane * 2] = make_float2(o0, o1);
    *(float2*)&out[(size_t)N_NODES * D + (size_t)n * D + lane * 2] = make_float2(av0, av1);
}

// ---------------------------------------------------------------------------
extern "C" void kernel_launch(void* const* d_in, const int* in_sizes, int n_in,
                              void* d_out, int out_size, void* d_ws, size_t ws_size,
                              hipStream_t stream)
{
    const float* x     = (const float*)d_in[0];
    const int*   eidx  = (const int*)d_in[1];
    const float* ewm   = (const float*)d_in[2];
    const float* ewv   = (const float*)d_in[3];
    const float* Wm    = (const float*)d_in[4];
    const float* bm    = (const float*)d_in[5];
    const float* Wv    = (const float*)d_in[6];
    const float* bv    = (const float*)d_in[7];
    const float* gamma = (const float*)d_in[8];
    const float* beta  = (const float*)d_in[9];
    const int* row = eidx;
    const int* col = eidx + N_EDGES;

    char* ws = (char*)d_ws;
    size_t off = 0;
    auto alloc = [&](size_t bytes) {
        void* p = ws + off;
        off += (bytes + 255) & ~(size_t)255;
        return p;
    };
    float2* hpack  = (float2*)alloc((size_t)N_NODES * D * 8);
    int*   counts  = (int*)alloc((size_t)N_NODES * 4);
    int*   rowstart= (int*)alloc((size_t)(N_NODES + 1) * 4);
    int*   cursor  = (int*)alloc((size_t)N_NODES * 4);
    float4* epack  = (float4*)alloc((size_t)N_EDGES * 16);
    int*   partials= (int*)alloc((size_t)SCAN_NB * 4);
    int*   blockoff= (int*)alloc((size_t)SCAN_NB * 4);

    hipMemsetAsync(counts, 0, (size_t)N_NODES * 4, stream);

    gemm_kernel<<<N_NODES / 64, 256, 0, stream>>>(x, Wm, bm, Wv, bv, hpack);
    hist_kernel<<<(N_EDGES + 255) / 256, 256, 0, stream>>>(row, counts);
    scan_partial_kernel<<<SCAN_NB, SCAN_B, 0, stream>>>(counts, partials);
    scan_top_kernel<<<1, 128, 0, stream>>>(partials, blockoff);
    scan_write_kernel<<<SCAN_NB, SCAN_B, 0, stream>>>(counts, blockoff, rowstart, cursor);
    scatter_kernel<<<(N_EDGES + 255) / 256, 256, 0, stream>>>(
        row, col, ewm, ewv, cursor, epack);
    agg_kernel<<<N_NODES / 4, 256, 0, stream>>>(
        (const float4*)hpack, rowstart, epack, gamma, beta, (float*)d_out);
}

// Round 5
// 172.137 us; speedup vs baseline: 1.2794x; 1.2794x over previous
//
#include <hip/hip_runtime.h>
#include <hip/hip_bf16.h>
#include <math.h>

#define N_NODES 40000
#define N_EDGES 640000
#define D 128
#define LN_EPS 1e-5f
#define SCAN_B 512
#define SCAN_NB ((N_NODES + SCAN_B - 1) / SCAN_B)   // 79

__device__ __forceinline__ float f4get(const float4& v, int j) {
    return j == 0 ? v.x : j == 1 ? v.y : j == 2 ? v.z : v.w;
}

// pack two floats as bf16 (RNE) into one uint: low16 = a, high16 = b
__device__ __forceinline__ unsigned bf2pack(float a, float b) {
    unsigned ua = __float_as_uint(a);
    ua = (ua + 0x7fffu + ((ua >> 16) & 1u)) >> 16;
    unsigned ub = __float_as_uint(b);
    ub = (ub + 0x7fffu + ((ub >> 16) & 1u)) >> 16;
    return ua | (ub << 16);
}
__device__ __forceinline__ float bflo(unsigned u) { return __uint_as_float(u << 16); }
__device__ __forceinline__ float bfhi(unsigned u) { return __uint_as_float(u & 0xffff0000u); }

// ---------------------------------------------------------------------------
// GEMM: hb[node] = 128 x (bf16 hm, bf16 hv) interleaved, 512B/row.
// hm = x@Wm+bm ; hv = exp(x@Wv+bv). f32 accumulate, bf16 store.
// ---------------------------------------------------------------------------
__global__ __launch_bounds__(256) void gemm_kernel(
    const float* __restrict__ x, const float* __restrict__ Wm,
    const float* __restrict__ bm, const float* __restrict__ Wv,
    const float* __restrict__ bv, uint4* __restrict__ hb)
{
    __shared__ float xs[64][24];
    __shared__ float wms[16][128];
    __shared__ float wvs[16][128];

    const int t = threadIdx.x;
    const int nbase = blockIdx.x * 64;
    const int tx = t & 31;
    const int ty = t >> 5;

    float accm[8][4] = {};
    float accv[8][4] = {};

    for (int k0 = 0; k0 < D; k0 += 16) {
        if (k0) __syncthreads();
        {
            int row = t >> 2, c4 = (t & 3) << 2;
            float4 v = *(const float4*)&x[(size_t)(nbase + row) * D + k0 + c4];
            xs[row][c4 + 0] = v.x; xs[row][c4 + 1] = v.y;
            xs[row][c4 + 2] = v.z; xs[row][c4 + 3] = v.w;
        }
        #pragma unroll
        for (int j = 0; j < 2; ++j) {
            int f4 = t + 256 * j;
            int row = f4 >> 5, c4 = (f4 & 31) << 2;
            *(float4*)&wms[row][c4] = *(const float4*)&Wm[(size_t)(k0 + row) * D + c4];
            *(float4*)&wvs[row][c4] = *(const float4*)&Wv[(size_t)(k0 + row) * D + c4];
        }
        __syncthreads();

        #pragma unroll
        for (int kk4 = 0; kk4 < 4; ++kk4) {
            float4 xr[8];
            #pragma unroll
            for (int r = 0; r < 8; ++r)
                xr[r] = *(float4*)&xs[ty * 8 + r][kk4 * 4];
            #pragma unroll
            for (int j = 0; j < 4; ++j) {
                float4 wm4 = *(float4*)&wms[kk4 * 4 + j][tx * 4];
                float4 wv4 = *(float4*)&wvs[kk4 * 4 + j][tx * 4];
                #pragma unroll
                for (int r = 0; r < 8; ++r) {
                    float xv = f4get(xr[r], j);
                    accm[r][0] = fmaf(xv, wm4.x, accm[r][0]);
                    accm[r][1] = fmaf(xv, wm4.y, accm[r][1]);
                    accm[r][2] = fmaf(xv, wm4.z, accm[r][2]);
                    accm[r][3] = fmaf(xv, wm4.w, accm[r][3]);
                    accv[r][0] = fmaf(xv, wv4.x, accv[r][0]);
                    accv[r][1] = fmaf(xv, wv4.y, accv[r][1]);
                    accv[r][2] = fmaf(xv, wv4.z, accv[r][2]);
                    accv[r][3] = fmaf(xv, wv4.w, accv[r][3]);
                }
            }
        }
    }

    float4 bm4 = *(const float4*)&bm[tx * 4];
    float4 bv4 = *(const float4*)&bv[tx * 4];
    #pragma unroll
    for (int r = 0; r < 8; ++r) {
        size_t node = nbase + ty * 8 + r;
        float m0 = accm[r][0] + bm4.x, m1 = accm[r][1] + bm4.y;
        float m2 = accm[r][2] + bm4.z, m3 = accm[r][3] + bm4.w;
        float v0 = expf(accv[r][0] + bv4.x), v1 = expf(accv[r][1] + bv4.y);
        float v2 = expf(accv[r][2] + bv4.z), v3 = expf(accv[r][3] + bv4.w);
        uint4 pk;
        pk.x = bf2pack(m0, v0);
        pk.y = bf2pack(m1, v1);
        pk.z = bf2pack(m2, v2);
        pk.w = bf2pack(m3, v3);
        hb[node * 32 + tx] = pk;
    }
}

// ---------------------------------------------------------------------------
__global__ void hist_kernel(const int* __restrict__ row, int* __restrict__ counts)
{
    int e = blockIdx.x * blockDim.x + threadIdx.x;
    if (e < N_EDGES) atomicAdd(&counts[row[e]], 1);
}

// ---------------------------------------------------------------------------
__global__ __launch_bounds__(SCAN_B) void scan_partial_kernel(
    const int* __restrict__ counts, int* __restrict__ partials)
{
    int idx = blockIdx.x * SCAN_B + threadIdx.x;
    int c = (idx < N_NODES) ? counts[idx] : 0;
    int lane = threadIdx.x & 63, wid = threadIdx.x >> 6;
    #pragma unroll
    for (int off = 32; off >= 1; off >>= 1) c += __shfl_xor(c, off);
    __shared__ int ws[SCAN_B / 64];
    if (lane == 0) ws[wid] = c;
    __syncthreads();
    if (threadIdx.x == 0) {
        int s = 0;
        #pragma unroll
        for (int i = 0; i < SCAN_B / 64; ++i) s += ws[i];
        partials[blockIdx.x] = s;
    }
}

// ---------------------------------------------------------------------------
__global__ __launch_bounds__(128) void scan_top_kernel(
    const int* __restrict__ partials, int* __restrict__ blockoff)
{
    __shared__ int tmp[128];
    int t = threadIdx.x;
    tmp[t] = (t < SCAN_NB) ? partials[t] : 0;
    __syncthreads();
    for (int off = 1; off < 128; off <<= 1) {
        int v = tmp[t];
        int a = (t >= off) ? tmp[t - off] : 0;
        __syncthreads();
        tmp[t] = v + a;
        __syncthreads();
    }
    if (t < SCAN_NB) blockoff[t] = (t > 0) ? tmp[t - 1] : 0;
}

// ---------------------------------------------------------------------------
__global__ __launch_bounds__(SCAN_B) void scan_write_kernel(
    const int* __restrict__ counts, const int* __restrict__ blockoff,
    int* __restrict__ rowstart, int* __restrict__ cursor)
{
    int idx = blockIdx.x * SCAN_B + threadIdx.x;
    int c = (idx < N_NODES) ? counts[idx] : 0;
    int lane = threadIdx.x & 63, wid = threadIdx.x >> 6;

    int inc = c;
    #pragma unroll
    for (int off = 1; off < 64; off <<= 1) {
        int u = __shfl_up(inc, off);
        if (lane >= off) inc += u;
    }
    __shared__ int ws[SCAN_B / 64];
    if (lane == 63) ws[wid] = inc;
    __syncthreads();
    if (threadIdx.x == 0) {
        int run = 0;
        #pragma unroll
        for (int i = 0; i < SCAN_B / 64; ++i) { int v = ws[i]; ws[i] = run; run += v; }
    }
    __syncthreads();
    int excl = inc - c + ws[wid] + blockoff[blockIdx.x];
    if (idx < N_NODES) {
        rowstart[idx] = excl;
        cursor[idx]   = excl;
        if (idx == N_NODES - 1) rowstart[N_NODES] = excl + c;
    }
}

// ---------------------------------------------------------------------------
// Scatter edges into CSR order, packed: epack[pos] = {colbits, wm, wv, 0}
// ---------------------------------------------------------------------------
__global__ void scatter_kernel(
    const int* __restrict__ row, const int* __restrict__ col,
    const float* __restrict__ ewm, const float* __restrict__ ewv,
    int* __restrict__ cursor, float4* __restrict__ epack)
{
    int e = blockIdx.x * blockDim.x + threadIdx.x;
    if (e >= N_EDGES) return;
    int r = row[e];
    int pos = atomicAdd(&cursor[r], 1);
    epack[pos] = make_float4(__int_as_float(col[e]), ewm[e], ewv[e], 0.0f);
}

// ---------------------------------------------------------------------------
// Per-node aggregation + degree norm + LayerNorm. One wave per node.
// bf16 table: 32 lanes x 16B cover a 512B row -> each half-wave handles one
// edge; 2 edges per wave-instruction. f32 accumulate, in-wave LN, no LDS.
// ---------------------------------------------------------------------------
__device__ __forceinline__ void accum_edge(
    const uint4& h, float wm, float wv, float (&am)[4], float (&av)[4])
{
    float wm2 = wm * wm;
    float mf, vf;
    mf = bflo(h.x); vf = bfhi(h.x);
    am[0] = fmaf(mf, wm, am[0]);
    av[0] = fmaf(wm2, vf, fmaf(mf * mf, wv, av[0]));
    mf = bflo(h.y); vf = bfhi(h.y);
    am[1] = fmaf(mf, wm, am[1]);
    av[1] = fmaf(wm2, vf, fmaf(mf * mf, wv, av[1]));
    mf = bflo(h.z); vf = bfhi(h.z);
    am[2] = fmaf(mf, wm, am[2]);
    av[2] = fmaf(wm2, vf, fmaf(mf * mf, wv, av[2]));
    mf = bflo(h.w); vf = bfhi(h.w);
    am[3] = fmaf(mf, wm, am[3]);
    av[3] = fmaf(wm2, vf, fmaf(mf * mf, wv, av[3]));
}

__global__ __launch_bounds__(256) void agg_kernel(
    const uint4* __restrict__ hb, const int* __restrict__ rowstart,
    const float4* __restrict__ epack,
    const float* __restrict__ gamma, const float* __restrict__ beta,
    float* __restrict__ out)
{
    const int wid  = threadIdx.x >> 6;
    const int lane = threadIdx.x & 63;
    const int half = lane >> 5;    // which edge of the pair
    const int sub  = lane & 31;    // 16B chunk within the row (4 feats)
    const int n = blockIdx.x * 4 + wid;

    const int start = rowstart[n];
    const int end   = rowstart[n + 1];

    float am[4] = {}, av[4] = {};

    int e = start;
    for (; e + 8 <= end; e += 8) {
        float4 m[4]; uint4 h[4];
        #pragma unroll
        for (int i = 0; i < 4; ++i) m[i] = epack[e + 2 * i + half];
        #pragma unroll
        for (int i = 0; i < 4; ++i) {
            int c = __float_as_int(m[i].x);
            h[i] = hb[(size_t)c * 32 + sub];
        }
        #pragma unroll
        for (int i = 0; i < 4; ++i) accum_edge(h[i], m[i].y, m[i].z, am, av);
    }
    for (; e + 2 <= end; e += 2) {
        float4 m = epack[e + half];
        int c = __float_as_int(m.x);
        uint4 h = hb[(size_t)c * 32 + sub];
        accum_edge(h, m.y, m.z, am, av);
    }
    if (e < end && half == 0) {
        float4 m = epack[e];
        int c = __float_as_int(m.x);
        uint4 h = hb[(size_t)c * 32 + sub];
        accum_edge(h, m.y, m.z, am, av);
    }

    // combine the two half-wave (even/odd edge) partials
    #pragma unroll
    for (int j = 0; j < 4; ++j) {
        am[j] += __shfl_xor(am[j], 32);
        av[j] += __shfl_xor(av[j], 32);
    }

    float degi = 1.0f / fmaxf((float)(end - start), 1.0f);
    float dg2 = degi * degi;
    #pragma unroll
    for (int j = 0; j < 4; ++j) { am[j] *= degi; av[j] *= dg2; }

    // LayerNorm over 128 feats: reduce within 32-lane half (halves identical)
    float s = am[0] + am[1] + am[2] + am[3];
    #pragma unroll
    for (int off = 16; off >= 1; off >>= 1) s += __shfl_xor(s, off);
    float mu = s * (1.0f / 128.0f);
    float d0 = am[0] - mu, d1 = am[1] - mu, d2 = am[2] - mu, d3 = am[3] - mu;
    float q = d0 * d0 + d1 * d1 + d2 * d2 + d3 * d3;
    #pragma unroll
    for (int off = 16; off >= 1; off >>= 1) q += __shfl_xor(q, off);
    float var = q * (1.0f / 128.0f);
    float rs = rsqrtf(var + LN_EPS);

    if (half == 0) {
        float4 g = *(const float4*)&gamma[sub * 4];
        float4 b = *(const float4*)&beta[sub * 4];
        float4 om = make_float4(fmaf(d0 * rs, g.x, b.x), fmaf(d1 * rs, g.y, b.y),
                                fmaf(d2 * rs, g.z, b.z), fmaf(d3 * rs, g.w, b.w));
        *(float4*)&out[(size_t)n * D + sub * 4] = om;
        *(float4*)&out[(size_t)N_NODES * D + (size_t)n * D + sub * 4] =
            make_float4(av[0], av[1], av[2], av[3]);
    }
}

// ---------------------------------------------------------------------------
extern "C" void kernel_launch(void* const* d_in, const int* in_sizes, int n_in,
                              void* d_out, int out_size, void* d_ws, size_t ws_size,
                              hipStream_t stream)
{
    const float* x     = (const float*)d_in[0];
    const int*   eidx  = (const int*)d_in[1];
    const float* ewm   = (const float*)d_in[2];
    const float* ewv   = (const float*)d_in[3];
    const float* Wm    = (const float*)d_in[4];
    const float* bm    = (const float*)d_in[5];
    const float* Wv    = (const float*)d_in[6];
    const float* bv    = (const float*)d_in[7];
    const float* gamma = (const float*)d_in[8];
    const float* beta  = (const float*)d_in[9];
    const int* row = eidx;
    const int* col = eidx + N_EDGES;

    char* ws = (char*)d_ws;
    size_t off = 0;
    auto alloc = [&](size_t bytes) {
        void* p = ws + off;
        off += (bytes + 255) & ~(size_t)255;
        return p;
    };
    uint4* hb      = (uint4*)alloc((size_t)N_NODES * 512);
    int*   counts  = (int*)alloc((size_t)N_NODES * 4);
    int*   rowstart= (int*)alloc((size_t)(N_NODES + 1) * 4);
    int*   cursor  = (int*)alloc((size_t)N_NODES * 4);
    float4* epack  = (float4*)alloc((size_t)N_EDGES * 16);
    int*   partials= (int*)alloc((size_t)SCAN_NB * 4);
    int*   blockoff= (int*)alloc((size_t)SCAN_NB * 4);

    hipMemsetAsync(counts, 0, (size_t)N_NODES * 4, stream);

    gemm_kernel<<<N_NODES / 64, 256, 0, stream>>>(x, Wm, bm, Wv, bv, hb);
    hist_kernel<<<(N_EDGES + 255) / 256, 256, 0, stream>>>(row, counts);
    scan_partial_kernel<<<SCAN_NB, SCAN_B, 0, stream>>>(counts, partials);
    scan_top_kernel<<<1, 128, 0, stream>>>(partials, blockoff);
    scan_write_kernel<<<SCAN_NB, SCAN_B, 0, stream>>>(counts, blockoff, rowstart, cursor);
    scatter_kernel<<<(N_EDGES + 255) / 256, 256, 0, stream>>>(
        row, col, ewm, ewv, cursor, epack);
    agg_kernel<<<N_NODES / 4, 256, 0, stream>>>(
        hb, rowstart, epack, gamma, beta, (float*)d_out);
}

// Round 6
// 144.363 us; speedup vs baseline: 1.5255x; 1.1924x over previous
//
#include <hip/hip_runtime.h>
#include <hip/hip_bf16.h>
#include <math.h>

#define N_NODES 40000
#define N_EDGES 640000
#define D 128
#define LN_EPS 1e-5f
#define SCAN_B 512
#define SCAN_NB ((N_NODES + SCAN_B - 1) / SCAN_B)   // 79

typedef __attribute__((ext_vector_type(8))) short bf16x8;
typedef __attribute__((ext_vector_type(4))) float f32x4;

// pack two floats as bf16 (RNE) into one uint: low16 = a, high16 = b
__device__ __forceinline__ unsigned bf2pack(float a, float b) {
    unsigned ua = __float_as_uint(a);
    ua = (ua + 0x7fffu + ((ua >> 16) & 1u)) >> 16;
    unsigned ub = __float_as_uint(b);
    ub = (ub + 0x7fffu + ((ub >> 16) & 1u)) >> 16;
    return ua | (ub << 16);
}
__device__ __forceinline__ unsigned short bfr(float a) {
    unsigned ua = __float_as_uint(a);
    return (unsigned short)((ua + 0x7fffu + ((ua >> 16) & 1u)) >> 16);
}
__device__ __forceinline__ float bflo(unsigned u) { return __uint_as_float(u << 16); }
__device__ __forceinline__ float bfhi(unsigned u) { return __uint_as_float(u & 0xffff0000u); }

// ---------------------------------------------------------------------------
// Pack W = [Wm | Wv] (128 x 256) into MFMA B-fragment order, bf16.
// Wpk[((kt*16 + nt)*64 + lane)*8 + j] = W[kt*32 + (lane>>4)*8 + j][nt*16 + (lane&15)]
// Also concat bias -> bcat[256].
// ---------------------------------------------------------------------------
__global__ __launch_bounds__(256) void packw_kernel(
    const float* __restrict__ Wm, const float* __restrict__ Wv,
    const float* __restrict__ bm, const float* __restrict__ bv,
    unsigned short* __restrict__ Wpk, float* __restrict__ bcat)
{
    int idx = blockIdx.x * 256 + threadIdx.x;   // 128 blocks -> 32768 threads
    int j  = idx & 7;
    int l  = (idx >> 3) & 63;
    int nt = (idx >> 9) & 15;
    int kt = idx >> 13;
    int k = kt * 32 + (l >> 4) * 8 + j;
    int c = nt * 16 + (l & 15);
    float w = (c < 128) ? Wm[k * 128 + c] : Wv[k * 128 + (c - 128)];
    Wpk[idx] = bfr(w);
    if (idx < 256) bcat[idx] = (idx < 128) ? bm[idx] : bv[idx - 128];
}

// ---------------------------------------------------------------------------
// MFMA GEMM + fused edge histogram.
// C[40000 x 256] = X[40000 x 128] @ [Wm|Wv]; hb = bf16-packed (hm, exp(hv_logit)).
// 625 blocks x 4 waves; wave = one 16-row tile, all 16 col-tiles. No LDS.
// ---------------------------------------------------------------------------
__global__ __launch_bounds__(256) void gemm_kernel(
    const float* __restrict__ x, const unsigned short* __restrict__ Wpk,
    const float* __restrict__ bcat, unsigned* __restrict__ hb,
    const int* __restrict__ row, int* __restrict__ counts)
{
    // fused histogram: 160000 threads x 4 edges
    {
        int gid = blockIdx.x * 256 + threadIdx.x;
        int4 r = ((const int4*)row)[gid];
        atomicAdd(&counts[r.x], 1);
        atomicAdd(&counts[r.y], 1);
        atomicAdd(&counts[r.z], 1);
        atomicAdd(&counts[r.w], 1);
    }

    const int w = threadIdx.x >> 6;
    const int l = threadIdx.x & 63;
    const int rbase = blockIdx.x * 64 + w * 16;
    const int arow = rbase + (l & 15);
    const int kqo = (l >> 4) * 8;

    // A fragments: 4 k-steps, 8 bf16 each, straight from global x (f32)
    bf16x8 a[4];
    #pragma unroll
    for (int kt = 0; kt < 4; ++kt) {
        const float* ap = &x[(size_t)arow * 128 + kt * 32 + kqo];
        float4 lo = *(const float4*)ap;
        float4 hi = *(const float4*)(ap + 4);
        uint4 au;
        au.x = bf2pack(lo.x, lo.y); au.y = bf2pack(lo.z, lo.w);
        au.z = bf2pack(hi.x, hi.y); au.w = bf2pack(hi.z, hi.w);
        a[kt] = *(bf16x8*)&au;
    }

    f32x4 acc[16];
    #pragma unroll
    for (int nt = 0; nt < 16; ++nt) acc[nt] = (f32x4){0.f, 0.f, 0.f, 0.f};

    const bf16x8* wp = (const bf16x8*)Wpk;
    #pragma unroll
    for (int kt = 0; kt < 4; ++kt) {
        #pragma unroll
        for (int nt = 0; nt < 16; ++nt) {
            bf16x8 b = wp[(kt * 16 + nt) * 64 + l];
            acc[nt] = __builtin_amdgcn_mfma_f32_16x16x32_bf16(a[kt], b, acc[nt], 0, 0, 0);
        }
    }

    // epilogue: D row = (l>>4)*4 + q, col = l&15 (m89-verified layout)
    const int c0 = l & 15;
    const int rq = rbase + (l >> 4) * 4;
    #pragma unroll
    for (int nt = 0; nt < 8; ++nt) {
        float bmv = bcat[nt * 16 + c0];
        float bvv = bcat[128 + nt * 16 + c0];
        #pragma unroll
        for (int q = 0; q < 4; ++q) {
            float m = acc[nt][q] + bmv;
            float v = expf(acc[nt + 8][q] + bvv);
            hb[(size_t)(rq + q) * 128 + nt * 16 + c0] = bf2pack(m, v);
        }
    }
}

// ---------------------------------------------------------------------------
__global__ __launch_bounds__(SCAN_B) void scan_partial_kernel(
    const int* __restrict__ counts, int* __restrict__ partials)
{
    int idx = blockIdx.x * SCAN_B + threadIdx.x;
    int c = (idx < N_NODES) ? counts[idx] : 0;
    int lane = threadIdx.x & 63, wid = threadIdx.x >> 6;
    #pragma unroll
    for (int off = 32; off >= 1; off >>= 1) c += __shfl_xor(c, off);
    __shared__ int ws[SCAN_B / 64];
    if (lane == 0) ws[wid] = c;
    __syncthreads();
    if (threadIdx.x == 0) {
        int s = 0;
        #pragma unroll
        for (int i = 0; i < SCAN_B / 64; ++i) s += ws[i];
        partials[blockIdx.x] = s;
    }
}

// ---------------------------------------------------------------------------
__global__ __launch_bounds__(128) void scan_top_kernel(
    const int* __restrict__ partials, int* __restrict__ blockoff)
{
    __shared__ int tmp[128];
    int t = threadIdx.x;
    tmp[t] = (t < SCAN_NB) ? partials[t] : 0;
    __syncthreads();
    for (int off = 1; off < 128; off <<= 1) {
        int v = tmp[t];
        int a = (t >= off) ? tmp[t - off] : 0;
        __syncthreads();
        tmp[t] = v + a;
        __syncthreads();
    }
    if (t < SCAN_NB) blockoff[t] = (t > 0) ? tmp[t - 1] : 0;
}

// ---------------------------------------------------------------------------
__global__ __launch_bounds__(SCAN_B) void scan_write_kernel(
    const int* __restrict__ counts, const int* __restrict__ blockoff,
    int* __restrict__ rowstart, int* __restrict__ cursor)
{
    int idx = blockIdx.x * SCAN_B + threadIdx.x;
    int c = (idx < N_NODES) ? counts[idx] : 0;
    int lane = threadIdx.x & 63, wid = threadIdx.x >> 6;

    int inc = c;
    #pragma unroll
    for (int off = 1; off < 64; off <<= 1) {
        int u = __shfl_up(inc, off);
        if (lane >= off) inc += u;
    }
    __shared__ int ws[SCAN_B / 64];
    if (lane == 63) ws[wid] = inc;
    __syncthreads();
    if (threadIdx.x == 0) {
        int run = 0;
        #pragma unroll
        for (int i = 0; i < SCAN_B / 64; ++i) { int v = ws[i]; ws[i] = run; run += v; }
    }
    __syncthreads();
    int excl = inc - c + ws[wid] + blockoff[blockIdx.x];
    if (idx < N_NODES) {
        rowstart[idx] = excl;
        cursor[idx]   = excl;
        if (idx == N_NODES - 1) rowstart[N_NODES] = excl + c;
    }
}

// ---------------------------------------------------------------------------
__global__ void scatter_kernel(
    const int* __restrict__ row, const int* __restrict__ col,
    const float* __restrict__ ewm, const float* __restrict__ ewv,
    int* __restrict__ cursor, float4* __restrict__ epack)
{
    int e = blockIdx.x * blockDim.x + threadIdx.x;
    if (e >= N_EDGES) return;
    int r = row[e];
    int pos = atomicAdd(&cursor[r], 1);
    epack[pos] = make_float4(__int_as_float(col[e]), ewm[e], ewv[e], 0.0f);
}

// ---------------------------------------------------------------------------
// Per-node aggregation + degree norm + LayerNorm. One wave per node.
// ---------------------------------------------------------------------------
__device__ __forceinline__ void accum_edge(
    const uint4& h, float wm, float wv, float (&am)[4], float (&av)[4])
{
    float wm2 = wm * wm;
    float mf, vf;
    mf = bflo(h.x); vf = bfhi(h.x);
    am[0] = fmaf(mf, wm, am[0]);
    av[0] = fmaf(wm2, vf, fmaf(mf * mf, wv, av[0]));
    mf = bflo(h.y); vf = bfhi(h.y);
    am[1] = fmaf(mf, wm, am[1]);
    av[1] = fmaf(wm2, vf, fmaf(mf * mf, wv, av[1]));
    mf = bflo(h.z); vf = bfhi(h.z);
    am[2] = fmaf(mf, wm, am[2]);
    av[2] = fmaf(wm2, vf, fmaf(mf * mf, wv, av[2]));
    mf = bflo(h.w); vf = bfhi(h.w);
    am[3] = fmaf(mf, wm, am[3]);
    av[3] = fmaf(wm2, vf, fmaf(mf * mf, wv, av[3]));
}

__global__ __launch_bounds__(256) void agg_kernel(
    const uint4* __restrict__ hb, const int* __restrict__ rowstart,
    const float4* __restrict__ epack,
    const float* __restrict__ gamma, const float* __restrict__ beta,
    float* __restrict__ out)
{
    const int wid  = threadIdx.x >> 6;
    const int lane = threadIdx.x & 63;
    const int half = lane >> 5;
    const int sub  = lane & 31;
    const int n = blockIdx.x * 4 + wid;

    const int start = rowstart[n];
    const int end   = rowstart[n + 1];

    float am[4] = {}, av[4] = {};

    int e = start;
    for (; e + 8 <= end; e += 8) {
        float4 m[4]; uint4 h[4];
        #pragma unroll
        for (int i = 0; i < 4; ++i) m[i] = epack[e + 2 * i + half];
        #pragma unroll
        for (int i = 0; i < 4; ++i) {
            int c = __float_as_int(m[i].x);
            h[i] = hb[(size_t)c * 32 + sub];
        }
        #pragma unroll
        for (int i = 0; i < 4; ++i) accum_edge(h[i], m[i].y, m[i].z, am, av);
    }
    for (; e + 2 <= end; e += 2) {
        float4 m = epack[e + half];
        int c = __float_as_int(m.x);
        uint4 h = hb[(size_t)c * 32 + sub];
        accum_edge(h, m.y, m.z, am, av);
    }
    if (e < end && half == 0) {
        float4 m = epack[e];
        int c = __float_as_int(m.x);
        uint4 h = hb[(size_t)c * 32 + sub];
        accum_edge(h, m.y, m.z, am, av);
    }

    #pragma unroll
    for (int j = 0; j < 4; ++j) {
        am[j] += __shfl_xor(am[j], 32);
        av[j] += __shfl_xor(av[j], 32);
    }

    float degi = 1.0f / fmaxf((float)(end - start), 1.0f);
    float dg2 = degi * degi;
    #pragma unroll
    for (int j = 0; j < 4; ++j) { am[j] *= degi; av[j] *= dg2; }

    float s = am[0] + am[1] + am[2] + am[3];
    #pragma unroll
    for (int off = 16; off >= 1; off >>= 1) s += __shfl_xor(s, off);
    float mu = s * (1.0f / 128.0f);
    float d0 = am[0] - mu, d1 = am[1] - mu, d2 = am[2] - mu, d3 = am[3] - mu;
    float q = d0 * d0 + d1 * d1 + d2 * d2 + d3 * d3;
    #pragma unroll
    for (int off = 16; off >= 1; off >>= 1) q += __shfl_xor(q, off);
    float var = q * (1.0f / 128.0f);
    float rs = rsqrtf(var + LN_EPS);

    if (half == 0) {
        float4 g = *(const float4*)&gamma[sub * 4];
        float4 b = *(const float4*)&beta[sub * 4];
        float4 om = make_float4(fmaf(d0 * rs, g.x, b.x), fmaf(d1 * rs, g.y, b.y),
                                fmaf(d2 * rs, g.z, b.z), fmaf(d3 * rs, g.w, b.w));
        *(float4*)&out[(size_t)n * D + sub * 4] = om;
        *(float4*)&out[(size_t)N_NODES * D + (size_t)n * D + sub * 4] =
            make_float4(av[0], av[1], av[2], av[3]);
    }
}

// ---------------------------------------------------------------------------
extern "C" void kernel_launch(void* const* d_in, const int* in_sizes, int n_in,
                              void* d_out, int out_size, void* d_ws, size_t ws_size,
                              hipStream_t stream)
{
    const float* x     = (const float*)d_in[0];
    const int*   eidx  = (const int*)d_in[1];
    const float* ewm   = (const float*)d_in[2];
    const float* ewv   = (const float*)d_in[3];
    const float* Wm    = (const float*)d_in[4];
    const float* bm    = (const float*)d_in[5];
    const float* Wv    = (const float*)d_in[6];
    const float* bv    = (const float*)d_in[7];
    const float* gamma = (const float*)d_in[8];
    const float* beta  = (const float*)d_in[9];
    const int* row = eidx;
    const int* col = eidx + N_EDGES;

    char* ws = (char*)d_ws;
    size_t off = 0;
    auto alloc = [&](size_t bytes) {
        void* p = ws + off;
        off += (bytes + 255) & ~(size_t)255;
        return p;
    };
    unsigned* hb          = (unsigned*)alloc((size_t)N_NODES * 512);
    unsigned short* Wpk   = (unsigned short*)alloc(32768 * 2);
    float*   bcat   = (float*)alloc(256 * 4);
    int*   counts  = (int*)alloc((size_t)N_NODES * 4);
    int*   rowstart= (int*)alloc((size_t)(N_NODES + 1) * 4);
    int*   cursor  = (int*)alloc((size_t)N_NODES * 4);
    float4* epack  = (float4*)alloc((size_t)N_EDGES * 16);
    int*   partials= (int*)alloc((size_t)SCAN_NB * 4);
    int*   blockoff= (int*)alloc((size_t)SCAN_NB * 4);

    hipMemsetAsync(counts, 0, (size_t)N_NODES * 4, stream);

    packw_kernel<<<128, 256, 0, stream>>>(Wm, Wv, bm, bv, Wpk, bcat);
    gemm_kernel<<<N_NODES / 64, 256, 0, stream>>>(x, Wpk, bcat, hb, row, counts);
    scan_partial_kernel<<<SCAN_NB, SCAN_B, 0, stream>>>(counts, partials);
    scan_top_kernel<<<1, 128, 0, stream>>>(partials, blockoff);
    scan_write_kernel<<<SCAN_NB, SCAN_B, 0, stream>>>(counts, blockoff, rowstart, cursor);
    scatter_kernel<<<(N_EDGES + 255) / 256, 256, 0, stream>>>(
        row, col, ewm, ewv, cursor, epack);
    agg_kernel<<<N_NODES / 4, 256, 0, stream>>>(
        (const uint4*)hb, rowstart, epack, gamma, beta, (float*)d_out);
}